// Round 4
// baseline (2244.005 us; speedup 1.0000x reference)
//
#include <hip/hip_runtime.h>
#include <math.h>

#define NE    8192
#define EDIM  256
#define LDIM  2048
#define BDIM  16
#define BL    (BDIM * LDIM)          // 32768 query vectors
#define ZQ_SIZE (BDIM * EDIM * LDIM) // 8388608
#define LOSS_IDX ZQ_SIZE
#define INDS_OFF (ZQ_SIZE + 1)
#define SZ_OFF   0                   // S_z[q] scratch in z_q region (K2 overwrites)
#define I2_OFF   32768               // idx2 scratch in z_q region (K2 overwrites)

// ---------------- K_sz: S_z[q] = fp32(sum z^2) per query; zero loss ----------
// thread = query; lane-consecutive q -> lane-consecutive l -> coalesced.
__global__ void vq_sz_kernel(const float* __restrict__ z,
                             float* __restrict__ out) {
    const int q = blockIdx.x * 256 + threadIdx.x;
    if (q == 0) out[LOSS_IDX] = 0.0f;
    const int b = q >> 11, l = q & 2047;
    const float* zb = z + (size_t)b * EDIM * LDIM + l;
    double acc = 0.0;
    #pragma unroll 8
    for (int c = 0; c < EDIM; ++c) {
        double v = (double)zb[(size_t)c * LDIM];
        acc = fma(v, v, acc);
    }
    out[SZ_OFF + q] = (float)acc;    // one rounding to fp32; binade-invariant
}

// ---------------- K1: fp32 GEMM + REFERENCE-QUANTIZED top-2 argmin -----------
// score[n] = fl32(S_z - 2*dot[n])  (S_e is absorbed by fp32 at |S_z|~256)
#define KC   32
#define LDSA 68
#define LDSB 132

__global__ __launch_bounds__(256, 2) void vq_argmin_kernel(
        const float* __restrict__ z, const float* __restrict__ cb,
        float* __restrict__ out) {
    __shared__ float As[KC][LDSA];   // As[k][i]
    __shared__ float Bs[KC][LDSB];   // Bs[k][n]

    const int t  = threadIdx.x;
    const int tx = t & 15;
    const int ty = t >> 4;
    const int i0 = blockIdx.x * 64;
    const int b  = i0 >> 11;
    const int l0 = i0 & 2047;
    const float* zbase = z + (size_t)b * EDIM * LDIM + l0;

    // S_z for this thread's 4 queries (written by K_sz, stream-ordered)
    float4 szv4 = *(const float4*)(out + SZ_OFF + i0 + 4 * ty);
    float szv[4] = {szv4.x, szv4.y, szv4.z, szv4.w};

    float v1[4], v2[4];
    int   i1[4], i2[4];
    #pragma unroll
    for (int r = 0; r < 4; ++r) { v1[r] = INFINITY; v2[r] = INFINITY; i1[r] = 0; i2[r] = 1; }

    const int kk = t >> 3;
    const int f4 = t & 7;

    for (int n0 = 0; n0 < NE; n0 += 128) {
        float acc[4][8];
        #pragma unroll
        for (int r = 0; r < 4; ++r)
            #pragma unroll
            for (int c = 0; c < 8; ++c) acc[r][c] = 0.0f;

        for (int kc = 0; kc < EDIM; kc += KC) {
            __syncthreads();
            {   // stage A: 64 queries x 32 dims, k-major
                const float* src = zbase + (size_t)(kc + kk) * LDIM;
                #pragma unroll
                for (int j = 0; j < 2; ++j) {
                    int f = f4 + 8 * j;
                    float4 v = *(const float4*)(src + 4 * f);
                    *(float4*)&As[kk][4 * f] = v;
                }
            }
            #pragma unroll
            for (int jn = 0; jn < 4; ++jn) {  // stage B transposed
                int nn = kk + 32 * jn;
                float4 v = *(const float4*)(cb + (size_t)(n0 + nn) * EDIM + kc + 4 * f4);
                Bs[4 * f4 + 0][nn] = v.x;
                Bs[4 * f4 + 1][nn] = v.y;
                Bs[4 * f4 + 2][nn] = v.z;
                Bs[4 * f4 + 3][nn] = v.w;
            }
            __syncthreads();
            #pragma unroll 4
            for (int k = 0; k < KC; ++k) {
                float4 av = *(const float4*)&As[k][4 * ty];
                float4 b0 = *(const float4*)&Bs[k][4 * tx];
                float4 b1 = *(const float4*)&Bs[k][64 + 4 * tx];
                float a[4]  = {av.x, av.y, av.z, av.w};
                float bb[8] = {b0.x, b0.y, b0.z, b0.w, b1.x, b1.y, b1.z, b1.w};
                #pragma unroll
                for (int r = 0; r < 4; ++r)
                    #pragma unroll
                    for (int c = 0; c < 8; ++c)
                        acc[r][c] = fmaf(a[r], bb[c], acc[r][c]);
            }
        }
        // epilogue: quantized score, per-thread top-2, first-index ties
        #pragma unroll
        for (int c = 0; c < 8; ++c) {
            int n = n0 + (c < 4 ? 4 * tx + c : 64 + 4 * tx + (c - 4));
            #pragma unroll
            for (int r = 0; r < 4; ++r) {
                float s = fmaf(-2.0f, acc[r][c], szv[r]);  // ONE fp32 rounding, like ref
                if (s < v1[r]) { v2[r] = v1[r]; i2[r] = i1[r]; v1[r] = s; i1[r] = n; }
                else if (s < v2[r]) { v2[r] = s; i2[r] = n; }
            }
        }
    }

    // merge top-2 pairs across the 16 lanes sharing ty (lexicographic ties)
    #pragma unroll
    for (int r = 0; r < 4; ++r) {
        float a1 = v1[r], a2 = v2[r];
        int   b1i = i1[r], b2i = i2[r];
        #pragma unroll
        for (int off = 1; off < 16; off <<= 1) {
            float o1 = __shfl_xor(a1, off, 64); int oi1 = __shfl_xor(b1i, off, 64);
            float o2 = __shfl_xor(a2, off, 64); int oi2 = __shfl_xor(b2i, off, 64);
            bool take = (o1 < a1) || (o1 == a1 && oi1 < b1i);
            float lv = take ? a1 : o1;  int li = take ? b1i : oi1;  // losing primary
            if (take) { a1 = o1; b1i = oi1; }
            if (o2 < a2 || (o2 == a2 && oi2 < b2i)) { a2 = o2; b2i = oi2; }
            if (lv < a2 || (lv == a2 && li < b2i)) { a2 = lv; b2i = li; }
        }
        if (tx == 0) {
            int q = i0 + 4 * ty + r;
            out[INDS_OFF + q] = (float)b1i;
            out[I2_OFF + q]   = (float)b2i;
        }
    }
}

// ---------------- K_verify: exact-dot quantized 2-candidate decision ---------
// one wave per query; removes my GEMM's ~5e-10 ordering noise at the top-2.
__global__ void vq_verify_kernel(const float* __restrict__ z,
                                 const float* __restrict__ cb,
                                 float* __restrict__ out) {
    const int t    = threadIdx.x;
    const int w    = t >> 6;
    const int lane = t & 63;
    const int q    = blockIdx.x * 4 + w;
    const int b    = q >> 11, l = q & 2047;
    const int c1 = (int)out[INDS_OFF + q];
    const int c2 = (int)out[I2_OFF + q];
    const float szq = out[SZ_OFF + q];
    const float* zb = z + (size_t)b * EDIM * LDIM + l;
    const float* r1 = cb + (size_t)c1 * EDIM;
    const float* r2 = cb + (size_t)c2 * EDIM;
    double d1 = 0.0, d2 = 0.0;
    #pragma unroll
    for (int j = 0; j < 4; ++j) {
        int d = lane + 64 * j;
        double zv = (double)zb[(size_t)d * LDIM];
        d1 = fma(zv, (double)r1[d], d1);
        d2 = fma(zv, (double)r2[d], d2);
    }
    #pragma unroll
    for (int off = 32; off; off >>= 1) {
        d1 += __shfl_xor(d1, off, 64);
        d2 += __shfl_xor(d2, off, 64);
    }
    if (lane == 0) {
        float s1 = fmaf(-2.0f, (float)d1, szq);   // quantized exactly as ref
        float s2 = fmaf(-2.0f, (float)d2, szq);
        int win = (s1 < s2) ? c1 : (s2 < s1 ? c2 : (c1 < c2 ? c1 : c2));
        out[INDS_OFF + q] = (float)win;
    }
}

// ---------------- K2: gather z_q, STE output, loss ----------------
__global__ void vq_output_kernel(const float* __restrict__ z,
                                 const float* __restrict__ cb,
                                 float* __restrict__ out) {
    __shared__ float rows[32 * 257];
    __shared__ float wsum[4];
    const float* indsf = out + INDS_OFF;
    const int t  = threadIdx.x;
    const int i0 = blockIdx.x * 32;
    const int b  = i0 >> 11;
    const int l0 = i0 & 2047;

    {
        int r  = t >> 3;
        int fb = t & 7;
        int idx = (int)indsf[i0 + r];
        const float* crow = cb + (size_t)idx * EDIM;
        #pragma unroll
        for (int j = 0; j < 8; ++j) {
            int f = fb + 8 * j;
            float4 v = *(const float4*)(crow + 4 * f);
            float* dst = &rows[r * 257 + 4 * f];
            dst[0] = v.x; dst[1] = v.y; dst[2] = v.z; dst[3] = v.w;
        }
    }
    __syncthreads();

    const int l  = t & 31;
    const int c0 = t >> 5;
    const size_t base = (size_t)b * EDIM * LDIM + l0 + l;
    float lsum = 0.0f;
    #pragma unroll 4
    for (int cc = 0; cc < 32; ++cc) {
        int c = c0 + 8 * cc;
        float q  = rows[l * 257 + c];
        float zv = z[base + (size_t)c * LDIM];
        float d  = q - zv;
        out[base + (size_t)c * LDIM] = zv + d;
        lsum += d * d;
    }
    #pragma unroll
    for (int off = 32; off; off >>= 1) lsum += __shfl_xor(lsum, off, 64);
    if ((t & 63) == 0) wsum[t >> 6] = lsum;
    __syncthreads();
    if (t == 0) {
        float s = wsum[0] + wsum[1] + wsum[2] + wsum[3];
        atomicAdd(out + LOSS_IDX, s * (1.1f / (float)ZQ_SIZE));
    }
}

extern "C" void kernel_launch(void* const* d_in, const int* in_sizes, int n_in,
                              void* d_out, int out_size, void* d_ws, size_t ws_size,
                              hipStream_t stream) {
    const float* z  = (const float*)d_in[0];   // (16, 256, 2048) fp32
    const float* cb = (const float*)d_in[1];   // (8192, 256) fp32
    float* out = (float*)d_out;
    (void)d_ws; (void)ws_size;

    // S_z per query -> out[0..32767]; zero loss.
    vq_sz_kernel<<<dim3(BL / 256), dim3(256), 0, stream>>>(z, out);
    // quantized top-2 argmin; idx1 -> inds, idx2 -> out[32768+q].
    vq_argmin_kernel<<<dim3(BL / 64), dim3(256), 0, stream>>>(z, cb, out);
    // exact-dot quantized decision between the two candidates.
    vq_verify_kernel<<<dim3(BL / 4), dim3(256), 0, stream>>>(z, cb, out);
    // gather + STE + loss (overwrites all scratch in z_q region).
    vq_output_kernel<<<dim3(BL / 32), dim3(256), 0, stream>>>(z, cb, out);
}

// Round 5
// 1006.375 us; speedup vs baseline: 2.2298x; 2.2298x over previous
//
#include <hip/hip_runtime.h>
#include <math.h>

#define NE    8192
#define EDIM  256
#define LDIM  2048
#define BL    32768
#define ZQ_SIZE 8388608
#define LOSS_IDX ZQ_SIZE
#define INDS_OFF (ZQ_SIZE + 1)

// scratch layout inside the z_q region of d_out (float offsets); K2 overwrites all of it last
#define BHI_F  0          // [8192][256] bf16 hi  (4MB)
#define BLO_F  1048576    // [8192][256] bf16 lo  (4MB)
#define PART_F 2097152    // [32 chunks][32768 q] ulonglong2 (16MB)
#define SZ_F   6291456    // 32768 f32
#define I2_F   (SZ_F + 32768)

typedef __attribute__((ext_vector_type(8))) short short8;
typedef __attribute__((ext_vector_type(4))) float float4v;

__device__ inline unsigned short f2bf(float f) {          // RNE float->bf16
    unsigned u = __float_as_uint(f);
    return (unsigned short)((u + 0x7FFFu + ((u >> 16) & 1u)) >> 16);
}
__device__ inline float bf2f(unsigned short h) {
    return __uint_as_float(((unsigned)h) << 16);
}
__device__ inline void pmerge(ulonglong2& a, const ulonglong2 b) {  // merge sorted pairs
    unsigned long long lo = a.x < b.x ? a.x : b.x;
    unsigned long long hi = a.x < b.x ? b.x : a.x;
    unsigned long long s2 = a.y < b.y ? a.y : b.y;
    a.x = lo; a.y = s2 < hi ? s2 : hi;
}

// ---------------- P1: split codebook into bf16 hi/lo ----------------
__global__ void vq_split_kernel(const float* __restrict__ cb, float* __restrict__ out) {
    unsigned short* BHI = (unsigned short*)(out + BHI_F);
    unsigned short* BLO = (unsigned short*)(out + BLO_F);
    const int t = threadIdx.x;
    const int row = blockIdx.x * 8 + (t >> 5);
    const int e0 = (t & 31) * 8;
    const float* src = cb + (size_t)row * EDIM + e0;
    float v[8];
    *(float4*)&v[0] = *(const float4*)src;
    *(float4*)&v[4] = *(const float4*)(src + 4);
    short8 h8, l8;
    #pragma unroll
    for (int j = 0; j < 8; ++j) {
        unsigned short h = f2bf(v[j]);
        h8[j] = (short)h;
        l8[j] = (short)f2bf(v[j] - bf2f(h));
    }
    *(short8*)(BHI + (size_t)row * EDIM + e0) = h8;
    *(short8*)(BLO + (size_t)row * EDIM + e0) = l8;
}

// ---------------- P2: S_z per query (fp64 sum -> fp32); zero loss ----------------
__global__ void vq_sz_kernel(const float* __restrict__ z, float* __restrict__ out) {
    const int q = blockIdx.x * 256 + threadIdx.x;
    if (q == 0) out[LOSS_IDX] = 0.0f;
    const int b = q >> 11, l = q & 2047;
    const float* zb = z + (size_t)b * EDIM * LDIM + l;
    double acc = 0.0;
    #pragma unroll 8
    for (int c = 0; c < EDIM; ++c) {
        double v = (double)zb[(size_t)c * LDIM];
        acc = fma(v, v, acc);
    }
    out[SZ_F + q] = (float)acc;
}

// ---------------- K1: MFMA split-bf16 distance GEMM + quantized top-2 ----------------
__global__ __launch_bounds__(512, 2) void vq_mfma_kernel(
        const float* __restrict__ z, float* __restrict__ out) {
    __shared__ __align__(16) unsigned short AhS[4 * 128 * 8];  // [oct][m][8]
    __shared__ __align__(16) unsigned short AlS[4 * 128 * 8];
    __shared__ __align__(16) unsigned short BhS[4 * 256 * 8];  // [oct][n][8]
    __shared__ __align__(16) unsigned short BlS[4 * 256 * 8];
    __shared__ ulonglong2 Sm[128 * 4];                         // [q_loc][wn]

    const unsigned short* BHI = (const unsigned short*)(out + BHI_F);
    const unsigned short* BLO = (const unsigned short*)(out + BLO_F);
    const float* Szp = out + SZ_F;
    ulonglong2* part = (ulonglong2*)(out + PART_F);

    const int t    = threadIdx.x;
    const int lane = t & 63;
    const int wave = t >> 6;
    const int m16  = lane & 15;
    const int quad = lane >> 4;
    const int wm   = wave >> 2;    // 0..1  (m half)
    const int wn   = wave & 3;     // 0..3  (n slice)

    const int q0 = blockIdx.x * 128;
    const int b  = q0 >> 11;
    const int l0 = q0 & 2047;
    const float* zbase = z + (size_t)b * (EDIM * LDIM) + l0;

    // S_z for this lane's 16 (fm,r) queries
    float szv[16];
    #pragma unroll
    for (int fm = 0; fm < 4; ++fm)
        #pragma unroll
        for (int r = 0; r < 4; ++r)
            szv[fm * 4 + r] = Szp[q0 + wm * 64 + fm * 16 + quad * 4 + r];

    // staging roles
    const int am   = t & 127;       // A row (m)
    const int aog  = t >> 7;        // A octet 0..3
    const int bn   = t & 255;       // B row (n)
    const int barr = t >> 8;        // 0=hi 1=lo
    const unsigned short* Bsrc = barr ? BLO : BHI;
    unsigned short* Bdst = barr ? BlS : BhS;

    float  apf[8];
    short8 bpf[4];
    // prefetch step 0
    #pragma unroll
    for (int j = 0; j < 8; ++j) apf[j] = zbase[(size_t)(aog * 8 + j) * LDIM + am];
    #pragma unroll
    for (int o = 0; o < 4; ++o) bpf[o] = *(const short8*)(Bsrc + (size_t)bn * EDIM + o * 8);

    float4v acc[4][4];

    for (int step = 0; step < 256; ++step) {
        if ((step & 7) == 0) {
            #pragma unroll
            for (int fm = 0; fm < 4; ++fm)
                #pragma unroll
                for (int fn = 0; fn < 4; ++fn)
                    acc[fm][fn] = (float4v){0.f, 0.f, 0.f, 0.f};
        }
        __syncthreads();   // previous mfma phase done with LDS
        // write staged regs -> LDS (A: split on the fly)
        {
            short8 h8, l8;
            #pragma unroll
            for (int j = 0; j < 8; ++j) {
                unsigned short h = f2bf(apf[j]);
                h8[j] = (short)h;
                l8[j] = (short)f2bf(apf[j] - bf2f(h));
            }
            *(short8*)&AhS[((aog << 7) + am) << 3] = h8;
            *(short8*)&AlS[((aog << 7) + am) << 3] = l8;
            #pragma unroll
            for (int o = 0; o < 4; ++o)
                *(short8*)&Bdst[((o << 8) + bn) << 3] = bpf[o];
        }
        // prefetch step+1 (overlaps mfma below)
        if (step < 255) {
            const int ns  = step + 1;
            const int nkc = (ns & 7) << 5;
            const int nn0 = (ns >> 3) << 8;
            #pragma unroll
            for (int j = 0; j < 8; ++j)
                apf[j] = zbase[(size_t)(nkc + aog * 8 + j) * LDIM + am];
            #pragma unroll
            for (int o = 0; o < 4; ++o)
                bpf[o] = *(const short8*)(Bsrc + (size_t)(nn0 + bn) * EDIM + nkc + o * 8);
        }
        __syncthreads();   // staging visible
        // mfma phase: 3-term split accumulate
        short8 bh[4], bl[4];
        #pragma unroll
        for (int fn = 0; fn < 4; ++fn) {
            const int n = wn * 64 + fn * 16 + m16;
            bh[fn] = *(const short8*)&BhS[((quad << 8) + n) << 3];
            bl[fn] = *(const short8*)&BlS[((quad << 8) + n) << 3];
        }
        #pragma unroll
        for (int fm = 0; fm < 4; ++fm) {
            const int m = wm * 64 + fm * 16 + m16;
            short8 ah = *(const short8*)&AhS[((quad << 7) + m) << 3];
            short8 al = *(const short8*)&AlS[((quad << 7) + m) << 3];
            #pragma unroll
            for (int fn = 0; fn < 4; ++fn) {
                acc[fm][fn] = __builtin_amdgcn_mfma_f32_16x16x32_bf16(ah, bh[fn], acc[fm][fn], 0, 0, 0);
                acc[fm][fn] = __builtin_amdgcn_mfma_f32_16x16x32_bf16(ah, bl[fn], acc[fm][fn], 0, 0, 0);
                acc[fm][fn] = __builtin_amdgcn_mfma_f32_16x16x32_bf16(al, bh[fn], acc[fm][fn], 0, 0, 0);
            }
        }
        if ((step & 7) == 7) {
            // chunk epilogue: quantized score -> u64 key -> top-2
            const int chunk = step >> 3;
            const int n0c   = chunk << 8;
            #pragma unroll
            for (int fm = 0; fm < 4; ++fm) {
                #pragma unroll
                for (int r = 0; r < 4; ++r) {
                    unsigned long long k1 = ~0ull, k2 = ~0ull;
                    #pragma unroll
                    for (int fn = 0; fn < 4; ++fn) {
                        float s = fmaf(-2.0f, acc[fm][fn][r], szv[fm * 4 + r]); // ONE fp32 rounding (ref semantics)
                        unsigned u = __float_as_uint(s);
                        unsigned mono = u ^ ((unsigned)(((int)u) >> 31) | 0x80000000u);
                        const int n = n0c + wn * 64 + fn * 16 + m16;
                        unsigned long long k = ((unsigned long long)mono << 32) | (unsigned)n;
                        if (k < k1) { k2 = k1; k1 = k; }
                        else if (k < k2) { k2 = k; }
                    }
                    #pragma unroll
                    for (int off = 1; off < 16; off <<= 1) {
                        unsigned long long o1 = __shfl_xor(k1, off, 64);
                        unsigned long long o2 = __shfl_xor(k2, off, 64);
                        unsigned long long lo = k1 < o1 ? k1 : o1;
                        unsigned long long hi = k1 < o1 ? o1 : k1;
                        k2 = k2 < o2 ? k2 : o2;
                        k2 = k2 < hi ? k2 : hi;
                        k1 = lo;
                    }
                    if (m16 == 0) {
                        const int ql = wm * 64 + fm * 16 + quad * 4 + r;
                        ulonglong2 v; v.x = k1; v.y = k2;
                        Sm[(ql << 2) + wn] = v;
                    }
                }
            }
            __syncthreads();
            if (t < 128) {   // merge 4 wave-slices, write partial
                ulonglong2 p = Sm[(t << 2) + 0];
                pmerge(p, Sm[(t << 2) + 1]);
                pmerge(p, Sm[(t << 2) + 2]);
                pmerge(p, Sm[(t << 2) + 3]);
                part[(size_t)chunk * BL + q0 + t] = p;
            }
        }
    }
}

// ---------------- K_merge: reduce 32 chunk partials per query ----------------
__global__ void vq_merge_kernel(float* __restrict__ out) {
    const ulonglong2* part = (const ulonglong2*)(out + PART_F);
    const int q = blockIdx.x * 256 + threadIdx.x;
    ulonglong2 g = part[q];
    for (int c = 1; c < 32; ++c) pmerge(g, part[(size_t)c * BL + q]);
    out[INDS_OFF + q] = (float)(unsigned)(g.x & 0xFFFFFFFFull);
    out[I2_F + q]     = (float)(unsigned)(g.y & 0xFFFFFFFFull);
}

// ---------------- K_verify: exact-dot quantized 2-candidate decision ----------------
__global__ void vq_verify_kernel(const float* __restrict__ z,
                                 const float* __restrict__ cb,
                                 float* __restrict__ out) {
    const int t    = threadIdx.x;
    const int w    = t >> 6;
    const int lane = t & 63;
    const int q    = blockIdx.x * 4 + w;
    const int b    = q >> 11, l = q & 2047;
    const int c1 = (int)out[INDS_OFF + q];
    const int c2 = (int)out[I2_F + q];
    const float szq = out[SZ_F + q];
    const float* zb = z + (size_t)b * EDIM * LDIM + l;
    const float* r1 = cb + (size_t)c1 * EDIM;
    const float* r2 = cb + (size_t)c2 * EDIM;
    double d1 = 0.0, d2 = 0.0;
    #pragma unroll
    for (int j = 0; j < 4; ++j) {
        int d = lane + 64 * j;
        double zv = (double)zb[(size_t)d * LDIM];
        d1 = fma(zv, (double)r1[d], d1);
        d2 = fma(zv, (double)r2[d], d2);
    }
    #pragma unroll
    for (int off = 32; off; off >>= 1) {
        d1 += __shfl_xor(d1, off, 64);
        d2 += __shfl_xor(d2, off, 64);
    }
    if (lane == 0) {
        float s1 = fmaf(-2.0f, (float)d1, szq);
        float s2 = fmaf(-2.0f, (float)d2, szq);
        int win = (s1 < s2) ? c1 : (s2 < s1 ? c2 : (c1 < c2 ? c1 : c2));
        out[INDS_OFF + q] = (float)win;
    }
}

// ---------------- K2: gather z_q, STE output, loss ----------------
__global__ void vq_output_kernel(const float* __restrict__ z,
                                 const float* __restrict__ cb,
                                 float* __restrict__ out) {
    __shared__ float rows[32 * 257];
    __shared__ float wsum[4];
    const float* indsf = out + INDS_OFF;
    const int t  = threadIdx.x;
    const int i0 = blockIdx.x * 32;
    const int b  = i0 >> 11;
    const int l0 = i0 & 2047;
    {
        int r  = t >> 3;
        int fb = t & 7;
        int idx = (int)indsf[i0 + r];
        const float* crow = cb + (size_t)idx * EDIM;
        #pragma unroll
        for (int j = 0; j < 8; ++j) {
            int f = fb + 8 * j;
            float4 v = *(const float4*)(crow + 4 * f);
            float* dst = &rows[r * 257 + 4 * f];
            dst[0] = v.x; dst[1] = v.y; dst[2] = v.z; dst[3] = v.w;
        }
    }
    __syncthreads();
    const int l  = t & 31;
    const int c0 = t >> 5;
    const size_t base = (size_t)b * EDIM * LDIM + l0 + l;
    float lsum = 0.0f;
    #pragma unroll 4
    for (int cc = 0; cc < 32; ++cc) {
        int c = c0 + 8 * cc;
        float q  = rows[l * 257 + c];
        float zv = z[base + (size_t)c * LDIM];
        float d  = q - zv;
        out[base + (size_t)c * LDIM] = zv + d;
        lsum += d * d;
    }
    #pragma unroll
    for (int off = 32; off; off >>= 1) lsum += __shfl_xor(lsum, off, 64);
    if ((t & 63) == 0) wsum[t >> 6] = lsum;
    __syncthreads();
    if (t == 0) {
        float s = wsum[0] + wsum[1] + wsum[2] + wsum[3];
        atomicAdd(out + LOSS_IDX, s * (1.1f / (float)ZQ_SIZE));
    }
}

extern "C" void kernel_launch(void* const* d_in, const int* in_sizes, int n_in,
                              void* d_out, int out_size, void* d_ws, size_t ws_size,
                              hipStream_t stream) {
    const float* z  = (const float*)d_in[0];   // (16, 256, 2048) fp32
    const float* cb = (const float*)d_in[1];   // (8192, 256) fp32
    float* out = (float*)d_out;
    (void)d_ws; (void)ws_size;

    vq_split_kernel <<<dim3(NE / 8),   dim3(256), 0, stream>>>(cb, out);
    vq_sz_kernel    <<<dim3(BL / 256), dim3(256), 0, stream>>>(z, out);
    vq_mfma_kernel  <<<dim3(BL / 128), dim3(512), 0, stream>>>(z, out);
    vq_merge_kernel <<<dim3(BL / 256), dim3(256), 0, stream>>>(out);
    vq_verify_kernel<<<dim3(BL / 4),   dim3(256), 0, stream>>>(z, cb, out);
    vq_output_kernel<<<dim3(BL / 32),  dim3(256), 0, stream>>>(z, cb, out);
}

// Round 6
// 689.808 us; speedup vs baseline: 3.2531x; 1.4589x over previous
//
#include <hip/hip_runtime.h>
#include <math.h>

#define NE    8192
#define EDIM  256
#define LDIM  2048
#define BL    32768
#define ZQ_SIZE 8388608
#define LOSS_IDX ZQ_SIZE
#define INDS_OFF (ZQ_SIZE + 1)

// scratch layout inside the z_q region of d_out (float offsets); K2 overwrites all of it last
#define BT_HI_F 0          // [32 oct][8192 n][8 k] bf16-hi, MFMA-frag-tiled (4MB)
#define BT_LO_F 1048576    // same, bf16-lo (4MB)
#define PART_F  2097152    // [32 chunks][32768 q] ulonglong2 (16MB)
#define SZ_F    6291456    // 32768 f32
#define I2_F    6324224    // 32768 f32

typedef __attribute__((ext_vector_type(8))) short short8;
typedef __attribute__((ext_vector_type(4))) float float4v;

__device__ __forceinline__ unsigned short f2bf(float f) {   // RNE float->bf16
    unsigned u = __float_as_uint(f);
    return (unsigned short)((u + 0x7FFFu + ((u >> 16) & 1u)) >> 16);
}
__device__ __forceinline__ float bf2f(unsigned short h) {
    return __uint_as_float(((unsigned)h) << 16);
}
__device__ __forceinline__ void pmerge(ulonglong2& a, const ulonglong2 b) { // merge sorted pairs
    unsigned long long lo = a.x < b.x ? a.x : b.x;
    unsigned long long hi = a.x < b.x ? b.x : a.x;
    unsigned long long s2 = a.y < b.y ? a.y : b.y;
    a.x = lo; a.y = s2 < hi ? s2 : hi;
}
__device__ __forceinline__ void gload_lds16(const void* g, void* l) {
    __builtin_amdgcn_global_load_lds(
        (const __attribute__((address_space(1))) unsigned int*)g,
        (__attribute__((address_space(3))) unsigned int*)l, 16, 0, 0);
}

// ---------------- P1: split codebook -> bf16 hi/lo, MFMA-frag tiling ----------------
// grid (32 rb, 32 oct); lane-consecutive rows -> coalesced 16B tiled writes.
__global__ void vq_bsplit_kernel(const float* __restrict__ cb, float* __restrict__ out) {
    unsigned short* Bth = (unsigned short*)(out + BT_HI_F);
    unsigned short* Btl = (unsigned short*)(out + BT_LO_F);
    const int oct = blockIdx.y;
    const int row = blockIdx.x * 256 + threadIdx.x;
    const float* src = cb + (size_t)row * EDIM + oct * 8;
    float v[8];
    *(float4*)&v[0] = *(const float4*)src;
    *(float4*)&v[4] = *(const float4*)(src + 4);
    short8 h8, l8;
    #pragma unroll
    for (int j = 0; j < 8; ++j) {
        unsigned short h = f2bf(v[j]);
        h8[j] = (short)h;
        l8[j] = (short)f2bf(v[j] - bf2f(h));
    }
    size_t o = ((size_t)(oct * NE + row)) << 3;
    *(short8*)(Bth + o) = h8;
    *(short8*)(Btl + o) = l8;
}

// ---------------- P2: S_z per query (fp64 sum -> fp32); zero loss ----------------
__global__ void vq_sz_kernel(const float* __restrict__ z, float* __restrict__ out) {
    const int q = blockIdx.x * 256 + threadIdx.x;
    if (q == 0) out[LOSS_IDX] = 0.0f;
    const int b = q >> 11, l = q & 2047;
    const float* zb = z + (size_t)b * EDIM * LDIM + l;
    double acc = 0.0;
    #pragma unroll 8
    for (int c = 0; c < EDIM; ++c) {
        double v = (double)zb[(size_t)c * LDIM];
        acc = fma(v, v, acc);
    }
    out[SZ_F + q] = (float)acc;
}

// ---------------- K1: MFMA split-bf16 distance GEMM + quantized top-2 ----------------
// 512 blocks: bid>>1 = 128-query tile, bid&1 = codebook half (16 chunks of 256 n).
__global__ __launch_bounds__(512, 4) void vq_mfma_kernel(
        const float* __restrict__ z, float* __restrict__ out) {
    __shared__ __align__(16) unsigned short AhS[4 * 128 * 8];  // [oct][m][8]  8KB
    __shared__ __align__(16) unsigned short AlS[4 * 128 * 8];
    __shared__ __align__(16) unsigned short BhS[4 * 256 * 8];  // [oct][n][8] 16KB
    __shared__ __align__(16) unsigned short BlS[4 * 256 * 8];
    __shared__ ulonglong2 Sm[128 * 4];                         // [q_loc][wn]  8KB

    const unsigned short* Bth = (const unsigned short*)(out + BT_HI_F);
    const unsigned short* Btl = (const unsigned short*)(out + BT_LO_F);
    const float* Szp = out + SZ_F;
    ulonglong2* part = (ulonglong2*)(out + PART_F);

    const int t    = threadIdx.x;
    const int lane = t & 63;
    const int wave = t >> 6;
    const int m16  = lane & 15;
    const int quad = lane >> 4;
    const int wm   = wave >> 2;    // 0..1  (m half)
    const int wn   = wave & 3;     // 0..3  (n slice)

    const int q0 = (blockIdx.x >> 1) * 128;
    const int nh = blockIdx.x & 1;
    const int b  = q0 >> 11;
    const int l0 = q0 & 2047;
    const float* zbase = z + (size_t)b * (EDIM * LDIM) + l0;

    float szv[16];
    #pragma unroll
    for (int fm = 0; fm < 4; ++fm)
        #pragma unroll
        for (int r = 0; r < 4; ++r)
            szv[fm * 4 + r] = Szp[q0 + wm * 64 + fm * 16 + quad * 4 + r];

    const int am  = t & 127;       // A row (m)
    const int aog = t >> 7;        // A octet 0..3

    float4v acc[4][4];

    for (int cl = 0; cl < 16; ++cl) {
        const int n0c = nh * 4096 + cl * 256;
        #pragma unroll
        for (int fm = 0; fm < 4; ++fm)
            #pragma unroll
            for (int fn = 0; fn < 4; ++fn)
                acc[fm][fn] = (float4v){0.f, 0.f, 0.f, 0.f};

        for (int ks = 0; ks < 8; ++ks) {
            const int kc = ks * 32;
            __syncthreads();   // previous MFMA phase done with LDS
            // --- A: load 8 fp32 (stride LDIM, lane-coalesced), cheap trunc split ---
            {
                const float* asrc = zbase + (size_t)(kc + aog * 8) * LDIM + am;
                float av[8];
                #pragma unroll
                for (int j = 0; j < 8; ++j) av[j] = asrc[(size_t)j * LDIM];
                short8 h8, l8;
                #pragma unroll
                for (int j = 0; j < 8; ++j) {
                    unsigned u  = __float_as_uint(av[j]);
                    unsigned hu = u & 0xFFFF0000u;
                    float rem   = av[j] - __uint_as_float(hu);
                    h8[j] = (short)(hu >> 16);
                    l8[j] = (short)(__float_as_uint(rem) >> 16);
                }
                *(short8*)&AhS[((aog << 7) + am) << 3] = h8;
                *(short8*)&AlS[((aog << 7) + am) << 3] = l8;
            }
            // --- B: 4 async global->LDS 16B issues per wave (frag-tiled source) ---
            #pragma unroll
            for (int p = 0; p < 4; ++p) {
                const int s   = wave * 4 + p;      // 0..31
                const int arr = s >> 4;            // 0=hi 1=lo
                const int oc  = (s >> 2) & 3;      // octet within step
                const int seg = s & 3;             // 64-n segment
                const int og  = ks * 4 + oc;       // global octet
                const unsigned short* src = (arr ? Btl : Bth)
                    + ((size_t)(og * NE + n0c + seg * 64 + lane) << 3);
                unsigned short* dst = (arr ? BlS : BhS)
                    + (((oc << 8) + seg * 64 + lane) << 3);
                gload_lds16(src, dst);
            }
            __syncthreads();   // staging visible
            // --- MFMA: 3-term split accumulate ---
            short8 bh[4], bl[4];
            #pragma unroll
            for (int fn = 0; fn < 4; ++fn) {
                const int n = wn * 64 + fn * 16 + m16;
                bh[fn] = *(const short8*)&BhS[((quad << 8) + n) << 3];
                bl[fn] = *(const short8*)&BlS[((quad << 8) + n) << 3];
            }
            #pragma unroll
            for (int fm = 0; fm < 4; ++fm) {
                const int m = wm * 64 + fm * 16 + m16;
                short8 ah = *(const short8*)&AhS[((quad << 7) + m) << 3];
                short8 al = *(const short8*)&AlS[((quad << 7) + m) << 3];
                #pragma unroll
                for (int fn = 0; fn < 4; ++fn) {
                    acc[fm][fn] = __builtin_amdgcn_mfma_f32_16x16x32_bf16(ah, bh[fn], acc[fm][fn], 0, 0, 0);
                    acc[fm][fn] = __builtin_amdgcn_mfma_f32_16x16x32_bf16(ah, bl[fn], acc[fm][fn], 0, 0, 0);
                    acc[fm][fn] = __builtin_amdgcn_mfma_f32_16x16x32_bf16(al, bh[fn], acc[fm][fn], 0, 0, 0);
                }
            }
        }
        // --- chunk epilogue: quantized score -> u64 key -> top-2 ---
        const int chunk_g = nh * 16 + cl;
        #pragma unroll
        for (int fm = 0; fm < 4; ++fm) {
            #pragma unroll
            for (int r = 0; r < 4; ++r) {
                unsigned long long k1 = ~0ull, k2 = ~0ull;
                #pragma unroll
                for (int fn = 0; fn < 4; ++fn) {
                    float s = fmaf(-2.0f, acc[fm][fn][r], szv[fm * 4 + r]); // ONE fp32 rounding (ref semantics)
                    unsigned u = __float_as_uint(s);
                    unsigned mono = u ^ ((unsigned)(((int)u) >> 31) | 0x80000000u);
                    const int n = n0c + wn * 64 + fn * 16 + m16;
                    unsigned long long k = ((unsigned long long)mono << 32) | (unsigned)n;
                    if (k < k1) { k2 = k1; k1 = k; }
                    else if (k < k2) { k2 = k; }
                }
                #pragma unroll
                for (int off = 1; off < 16; off <<= 1) {
                    unsigned long long o1 = __shfl_xor(k1, off, 64);
                    unsigned long long o2 = __shfl_xor(k2, off, 64);
                    unsigned long long lo = k1 < o1 ? k1 : o1;
                    unsigned long long hi = k1 < o1 ? o1 : k1;
                    k2 = k2 < o2 ? k2 : o2;
                    k2 = k2 < hi ? k2 : hi;
                    k1 = lo;
                }
                if (m16 == 0) {
                    const int ql = wm * 64 + fm * 16 + quad * 4 + r;
                    ulonglong2 v; v.x = k1; v.y = k2;
                    Sm[(ql << 2) + wn] = v;
                }
            }
        }
        __syncthreads();
        if (t < 128) {   // merge 4 wave-slices, write partial
            ulonglong2 p = Sm[(t << 2) + 0];
            pmerge(p, Sm[(t << 2) + 1]);
            pmerge(p, Sm[(t << 2) + 2]);
            pmerge(p, Sm[(t << 2) + 3]);
            part[(size_t)chunk_g * BL + q0 + t] = p;
        }
    }
}

// ---------------- K_merge: reduce 32 chunk partials per query ----------------
__global__ void vq_merge_kernel(float* __restrict__ out) {
    const ulonglong2* part = (const ulonglong2*)(out + PART_F);
    const int q = blockIdx.x * 256 + threadIdx.x;
    ulonglong2 g = part[q];
    for (int c = 1; c < 32; ++c) pmerge(g, part[(size_t)c * BL + q]);
    out[INDS_OFF + q] = (float)(unsigned)(g.x & 0xFFFFFFFFull);
    out[I2_F + q]     = (float)(unsigned)(g.y & 0xFFFFFFFFull);
}

// ---------------- K_verify: exact-dot quantized 2-candidate decision ----------------
__global__ void vq_verify_kernel(const float* __restrict__ z,
                                 const float* __restrict__ cb,
                                 float* __restrict__ out) {
    const int t    = threadIdx.x;
    const int w    = t >> 6;
    const int lane = t & 63;
    const int q    = blockIdx.x * 4 + w;
    const int b    = q >> 11, l = q & 2047;
    const int c1 = (int)out[INDS_OFF + q];
    const int c2 = (int)out[I2_F + q];
    const float szq = out[SZ_F + q];
    const float* zb = z + (size_t)b * EDIM * LDIM + l;
    const float* r1 = cb + (size_t)c1 * EDIM;
    const float* r2 = cb + (size_t)c2 * EDIM;
    double d1 = 0.0, d2 = 0.0;
    #pragma unroll
    for (int j = 0; j < 4; ++j) {
        int d = lane + 64 * j;
        double zv = (double)zb[(size_t)d * LDIM];
        d1 = fma(zv, (double)r1[d], d1);
        d2 = fma(zv, (double)r2[d], d2);
    }
    #pragma unroll
    for (int off = 32; off; off >>= 1) {
        d1 += __shfl_xor(d1, off, 64);
        d2 += __shfl_xor(d2, off, 64);
    }
    if (lane == 0) {
        float s1 = fmaf(-2.0f, (float)d1, szq);
        float s2 = fmaf(-2.0f, (float)d2, szq);
        int win = (s1 < s2) ? c1 : (s2 < s1 ? c2 : (c1 < c2 ? c1 : c2));
        out[INDS_OFF + q] = (float)win;
    }
}

// ---------------- K2: gather z_q, STE output, loss ----------------
__global__ void vq_output_kernel(const float* __restrict__ z,
                                 const float* __restrict__ cb,
                                 float* __restrict__ out) {
    __shared__ float rows[32 * 257];
    __shared__ float wsum[4];
    const float* indsf = out + INDS_OFF;
    const int t  = threadIdx.x;
    const int i0 = blockIdx.x * 32;
    const int b  = i0 >> 11;
    const int l0 = i0 & 2047;
    {
        int r  = t >> 3;
        int fb = t & 7;
        int idx = (int)indsf[i0 + r];
        const float* crow = cb + (size_t)idx * EDIM;
        #pragma unroll
        for (int j = 0; j < 8; ++j) {
            int f = fb + 8 * j;
            float4 v = *(const float4*)(crow + 4 * f);
            float* dst = &rows[r * 257 + 4 * f];
            dst[0] = v.x; dst[1] = v.y; dst[2] = v.z; dst[3] = v.w;
        }
    }
    __syncthreads();
    const int l  = t & 31;
    const int c0 = t >> 5;
    const size_t base = (size_t)b * EDIM * LDIM + l0 + l;
    float lsum = 0.0f;
    #pragma unroll 4
    for (int cc = 0; cc < 32; ++cc) {
        int c = c0 + 8 * cc;
        float q  = rows[l * 257 + c];
        float zv = z[base + (size_t)c * LDIM];
        float d  = q - zv;
        out[base + (size_t)c * LDIM] = zv + d;
        lsum += d * d;
    }
    #pragma unroll
    for (int off = 32; off; off >>= 1) lsum += __shfl_xor(lsum, off, 64);
    if ((t & 63) == 0) wsum[t >> 6] = lsum;
    __syncthreads();
    if (t == 0) {
        float s = wsum[0] + wsum[1] + wsum[2] + wsum[3];
        atomicAdd(out + LOSS_IDX, s * (1.1f / (float)ZQ_SIZE));
    }
}

extern "C" void kernel_launch(void* const* d_in, const int* in_sizes, int n_in,
                              void* d_out, int out_size, void* d_ws, size_t ws_size,
                              hipStream_t stream) {
    const float* z  = (const float*)d_in[0];   // (16, 256, 2048) fp32
    const float* cb = (const float*)d_in[1];   // (8192, 256) fp32
    float* out = (float*)d_out;
    (void)d_ws; (void)ws_size;

    vq_bsplit_kernel<<<dim3(32, 32),   dim3(256), 0, stream>>>(cb, out);
    vq_sz_kernel    <<<dim3(BL / 256), dim3(256), 0, stream>>>(z, out);
    vq_mfma_kernel  <<<dim3(BL / 64),  dim3(512), 0, stream>>>(z, out);   // 512 blocks
    vq_merge_kernel <<<dim3(BL / 256), dim3(256), 0, stream>>>(out);
    vq_verify_kernel<<<dim3(BL / 4),   dim3(256), 0, stream>>>(z, cb, out);
    vq_output_kernel<<<dim3(BL / 32),  dim3(256), 0, stream>>>(z, cb, out);
}